// Round 10
// baseline (809.889 us; speedup 1.0000x reference)
//
#include <hip/hip_runtime.h>
#include <hip/hip_bf16.h>
#include <math.h>

#define CC0 2000
#define CC1 10000
#define CC2 50000
#define DH  1024
#define BATCH 4096
#define OUT_HEAD (CC0 + 2)

#define N0_P 8192    // tail0 proj rows padded (8000 -> 8192),  mult of 128
#define N1_P 40192   // tail1 proj rows padded (40000 -> 40192), mult of 128
#define NH_P 2048    // head rows padded (2002 -> 2048)

typedef __attribute__((ext_vector_type(4))) float  f32x4;
typedef __attribute__((ext_vector_type(8))) __bf16 bf16x8;
typedef __attribute__((ext_vector_type(8))) short  s16x8;

__device__ __forceinline__ void gload_lds16(const void* g, void* l) {
    __builtin_amdgcn_global_load_lds(
        (const __attribute__((address_space(1))) void*)g,
        (__attribute__((address_space(3))) void*)l, 16, 0, 0);
}

// ------- fp32 -> bf16 conversions (6 segments) + rowsum zeroing (segment 6) -------
__global__ __launch_bounds__(256) void convert_all_kernel(
    const float4* __restrict__ s0, ushort4* __restrict__ d0, int n0s, int n0d,
    const float4* __restrict__ s1, ushort4* __restrict__ d1, int n1s, int n1d,
    const float4* __restrict__ s2, ushort4* __restrict__ d2, int n2s, int n2d,
    const float4* __restrict__ s3, ushort4* __restrict__ d3, int n3s, int n3d,
    const float4* __restrict__ s4, ushort4* __restrict__ d4, int n4s, int n4d,
    const float4* __restrict__ s5, ushort4* __restrict__ d5, int n5s, int n5d,
    float* __restrict__ rs0, float* __restrict__ rs1)
{
    if (blockIdx.y == 6) {
        int i = blockIdx.x * blockDim.x + threadIdx.x;
        if (i < BATCH) { rs0[i] = 0.f; rs1[i] = 0.f; }
        return;
    }
    const float4* src; ushort4* dst; int ns, nd;
    switch (blockIdx.y) {
        case 0: src = s0; dst = d0; ns = n0s; nd = n0d; break;
        case 1: src = s1; dst = d1; ns = n1s; nd = n1d; break;
        case 2: src = s2; dst = d2; ns = n2s; nd = n2d; break;
        case 3: src = s3; dst = d3; ns = n3s; nd = n3d; break;
        case 4: src = s4; dst = d4; ns = n4s; nd = n4d; break;
        default: src = s5; dst = d5; ns = n5s; nd = n5d; break;
    }
    int i = blockIdx.x * blockDim.x + threadIdx.x;
    const int stride = gridDim.x * blockDim.x;
    for (; i < nd; i += stride) {
        ushort4 o = {0, 0, 0, 0};
        if (i < ns) {
            float4 v = src[i];
            o.x = __builtin_bit_cast(unsigned short, (__bf16)v.x);
            o.y = __builtin_bit_cast(unsigned short, (__bf16)v.y);
            o.z = __builtin_bit_cast(unsigned short, (__bf16)v.z);
            o.w = __builtin_bit_cast(unsigned short, (__bf16)v.w);
        }
        dst[i] = o;
    }
}

// ======== shared m97-style 128x128 GEMM tile body (4 waves, 64x64 per wave) ========
// acc layout: row = bm + wr*64 + m*16 + lg*4 + r; col = bn + wc*64 + n*16 + lr
struct TileCtx {
    int bm, bn, lr, lg, wr, wc, w, lrow, lcol, t, lane;
};

__device__ __forceinline__ void gemm128_mainloop(
    const ushort* __restrict__ A, const ushort* __restrict__ B, int K,
    const TileCtx& c, ushort* As, ushort* Bs, f32x4 acc[4][4])
{
    for (int k0 = 0; k0 < K; k0 += 64) {
        #pragma unroll
        for (int i = 0; i < 4; ++i) {
            const int seg = c.w * 4 + i;
            const int row = seg * 8 + c.lrow;
            gload_lds16(A + (size_t)(c.bm + row) * K + k0 + c.lcol, &As[seg * 512]);
            gload_lds16(B + (size_t)(c.bn + row) * K + k0 + c.lcol, &Bs[seg * 512]);
        }
        __syncthreads();
        #pragma unroll
        for (int ks = 0; ks < 2; ++ks) {
            s16x8 af[4], bfr[4];
            #pragma unroll
            for (int m = 0; m < 4; ++m)
                af[m] = *(const s16x8*)&As[(c.wr * 64 + m * 16 + c.lr) * 64 + ks * 32 + c.lg * 8];
            #pragma unroll
            for (int n = 0; n < 4; ++n)
                bfr[n] = *(const s16x8*)&Bs[(c.wc * 64 + n * 16 + c.lr) * 64 + ks * 32 + c.lg * 8];
            #pragma unroll
            for (int m = 0; m < 4; ++m)
                #pragma unroll
                for (int n = 0; n < 4; ++n)
                    acc[m][n] = __builtin_amdgcn_mfma_f32_16x16x32_bf16(
                        __builtin_bit_cast(bf16x8, af[m]),
                        __builtin_bit_cast(bf16x8, bfr[n]), acc[m][n], 0, 0, 0);
        }
        __syncthreads();
    }
}

__device__ __forceinline__ TileCtx make_ctx(int bm, int bn, int t) {
    TileCtx c;
    c.t = t; c.lane = t & 63; c.w = t >> 6;
    c.wr = c.w >> 1; c.wc = c.w & 1;
    c.lr = c.lane & 15; c.lg = c.lane >> 4;
    c.bm = bm; c.bn = bn;
    c.lrow = c.lane >> 3; c.lcol = (c.lane & 7) * 8;
    return c;
}

// ------- fused small GEMMs: h0 = x@W0a^T (bf16), h1 = x@W1a^T (bf16), headL = x@Wh^T (f32)
__global__ __launch_bounds__(256) void gemm128x3_kernel(
    const ushort* __restrict__ x_bf,
    const ushort* __restrict__ W0a_bf, ushort* __restrict__ h0,
    const ushort* __restrict__ W1a_bf, ushort* __restrict__ h1,
    const ushort* __restrict__ Wh_bf,  float*  __restrict__ headL)
{
    __shared__ ushort As[128 * 64];
    __shared__ ushort Bs[128 * 64];

    const int gb = blockIdx.x;
    const ushort* B; void* C;
    int N, ldC, wmode, nbx, lin;
    if (gb < 256)      { B = W0a_bf; C = h0;    N = DH;       ldC = DH;       wmode = 1; nbx = 8;  lin = gb; }
    else if (gb < 320) { B = W1a_bf; C = h1;    N = 256;      ldC = 256;      wmode = 1; nbx = 2;  lin = gb - 256; }
    else               { B = Wh_bf;  C = headL; N = OUT_HEAD; ldC = OUT_HEAD; wmode = 2; nbx = 16; lin = gb - 320; }

    const int nwg = nbx * 32;
    const int q = nwg >> 3;
    int bid = (lin & 7) * q + (lin >> 3);
    const int bx = bid % nbx;
    const int by = bid / nbx;

    TileCtx c = make_ctx(by * 128, bx * 128, threadIdx.x);
    f32x4 acc[4][4] = {};
    gemm128_mainloop(x_bf, B, DH, c, As, Bs, acc);

    #pragma unroll
    for (int m = 0; m < 4; ++m)
        #pragma unroll
        for (int r = 0; r < 4; ++r) {
            const int row = c.bm + c.wr * 64 + m * 16 + c.lg * 4 + r;
            #pragma unroll
            for (int n = 0; n < 4; ++n) {
                const int col = c.bn + c.wc * 64 + n * 16 + c.lr;
                float v = acc[m][n][r];
                if (col < N) {
                    if (wmode == 1)
                        ((ushort*)C)[(size_t)row * ldC + col] =
                            __builtin_bit_cast(unsigned short, (__bf16)v);
                    else
                        ((float*)C)[(size_t)row * ldC + col] = v;
                }
            }
        }
}

// ------- fused tail GEMMs: seg0 = tail0 (K=1024, bf16 C + sumexp),
//                            seg1 = tail1 pass1 (K=256, sumexp only)
__global__ __launch_bounds__(256) void tails_gemm_kernel(
    const ushort* __restrict__ h0, const ushort* __restrict__ W0b,
    ushort* __restrict__ L0, float* __restrict__ rs0,
    const ushort* __restrict__ h1, const ushort* __restrict__ W1b,
    float* __restrict__ rs1)
{
    __shared__ ushort As[128 * 64];
    __shared__ ushort Bs[128 * 64];

    const int gb = blockIdx.x;
    const ushort *A, *B; ushort* C; float* rsum;
    int K, N, nbx, ldC, lin, wstore;
    if (gb < 2048) { A = h0; B = W0b; C = L0;      rsum = rs0; K = DH;  N = CC1 - CC0; nbx = N0_P / 128; ldC = N0_P; lin = gb;        wstore = 1; }
    else           { A = h1; B = W1b; C = nullptr; rsum = rs1; K = 256; N = CC2 - CC1; nbx = N1_P / 128; ldC = 0;    lin = gb - 2048; wstore = 0; }

    const int nwg = nbx * 32;
    const int q = nwg >> 3;
    int bid = (lin & 7) * q + (lin >> 3);
    const int by = bid % 32;   // panel-major: consecutive bids share B panel (bx)
    const int bx = bid / 32;

    TileCtx c = make_ctx(by * 128, bx * 128, threadIdx.x);
    f32x4 acc[4][4] = {};
    gemm128_mainloop(A, B, K, c, As, Bs, acc);

    #pragma unroll
    for (int m = 0; m < 4; ++m)
        #pragma unroll
        for (int r = 0; r < 4; ++r) {
            const int row = c.bm + c.wr * 64 + m * 16 + c.lg * 4 + r;
            float psum = 0.f;
            #pragma unroll
            for (int n = 0; n < 4; ++n) {
                const int col = c.bn + c.wc * 64 + n * 16 + c.lr;
                float v = acc[m][n][r];
                if (col < N) {
                    if (wstore)
                        C[(size_t)row * ldC + col] =
                            __builtin_bit_cast(unsigned short, (__bf16)v);
                    psum += __expf(v);   // logits O(1): max-free LSE safe
                }
            }
            #pragma unroll
            for (int s = 1; s < 16; s <<= 1) psum += __shfl_xor(psum, s, 64);
            if (c.lr == 0) atomicAdd(&rsum[row], psum);
        }
}

// ------- fused: seg0 = tail1 pass2 (K=256, f32 C + add1[row]), seg1 = tail0 finalize
__global__ __launch_bounds__(256) void p2_fin_kernel(
    const ushort* __restrict__ h1, const ushort* __restrict__ W1b,
    float* __restrict__ out, const float* __restrict__ add1,
    const ushort* __restrict__ L0, const float* __restrict__ add0)
{
    __shared__ ushort As[128 * 64];
    __shared__ ushort Bs[128 * 64];

    const int gb = blockIdx.x;
    const int NGEMM = (N1_P / 128) * 32;   // 10048
    if (gb >= NGEMM) {
        // ---- tail0 finalize: out[:,2000:10000] = bf16(L0) + add0[row]
        const int idx = gb - NGEMM;        // 0..16383
        const int row = idx >> 2;
        const int ch  = (idx & 3) * 256 + threadIdx.x;   // ushort8 chunk within row
        if (ch < 1000) {
            const float add = add0[row];
            s16x8 v = *(const s16x8*)(L0 + (size_t)row * N0_P + ch * 8);
            float* o = out + (size_t)row * CC2 + CC0 + ch * 8;
            float4 o0, o1;
            o0.x = __builtin_bit_cast(float, (unsigned)(unsigned short)v[0] << 16) + add;
            o0.y = __builtin_bit_cast(float, (unsigned)(unsigned short)v[1] << 16) + add;
            o0.z = __builtin_bit_cast(float, (unsigned)(unsigned short)v[2] << 16) + add;
            o0.w = __builtin_bit_cast(float, (unsigned)(unsigned short)v[3] << 16) + add;
            o1.x = __builtin_bit_cast(float, (unsigned)(unsigned short)v[4] << 16) + add;
            o1.y = __builtin_bit_cast(float, (unsigned)(unsigned short)v[5] << 16) + add;
            o1.z = __builtin_bit_cast(float, (unsigned)(unsigned short)v[6] << 16) + add;
            o1.w = __builtin_bit_cast(float, (unsigned)(unsigned short)v[7] << 16) + add;
            *(float4*)o = o0;
            *(float4*)(o + 4) = o1;
        }
        return;
    }

    // ---- tail1 pass2: recompute GEMM, write normalized fp32 to out
    const int nbx = N1_P / 128;
    const int nwg = nbx * 32;
    const int q = nwg >> 3;
    int bid = ((gb & 7) * q) + (gb >> 3);
    const int by = bid % 32;
    const int bx = bid / 32;

    TileCtx c = make_ctx(by * 128, bx * 128, threadIdx.x);
    f32x4 acc[4][4] = {};
    gemm128_mainloop(h1, W1b, 256, c, As, Bs, acc);

    #pragma unroll
    for (int m = 0; m < 4; ++m)
        #pragma unroll
        for (int r = 0; r < 4; ++r) {
            const int row = c.bm + c.wr * 64 + m * 16 + c.lg * 4 + r;
            const float add = add1[row];
            #pragma unroll
            for (int n = 0; n < 4; ++n) {
                const int col = c.bn + c.wc * 64 + n * 16 + c.lr;
                if (col < CC2 - CC1)
                    out[(size_t)row * CC2 + CC1 + col] = acc[m][n][r] + add;
            }
        }
}

// ---------------- head log-softmax: one block per row ----------------
__global__ __launch_bounds__(256) void head_lsm_kernel(
    const float* __restrict__ HL, const float* __restrict__ bh,
    float* __restrict__ out, float* __restrict__ s01)
{
    const int row = blockIdx.x;
    const float* L = HL + (size_t)row * OUT_HEAD;
    const int t = threadIdx.x;
    __shared__ float red[4];

    float m = -1e30f;
    for (int i = t; i < OUT_HEAD; i += 256) m = fmaxf(m, L[i] + bh[i]);
    #pragma unroll
    for (int s = 1; s < 64; s <<= 1) m = fmaxf(m, __shfl_xor(m, s, 64));
    if ((t & 63) == 0) red[t >> 6] = m;
    __syncthreads();
    m = fmaxf(fmaxf(red[0], red[1]), fmaxf(red[2], red[3]));

    float sum = 0.f;
    for (int i = t; i < OUT_HEAD; i += 256) sum += __expf(L[i] + bh[i] - m);
    #pragma unroll
    for (int s = 1; s < 64; s <<= 1) sum += __shfl_xor(sum, s, 64);
    __syncthreads();
    if ((t & 63) == 0) red[t >> 6] = sum;
    __syncthreads();
    const float lse = m + logf(red[0] + red[1] + red[2] + red[3]);

    float* orow = out + (size_t)row * CC2;
    for (int i = t; i < CC0; i += 256) orow[i] = L[i] + bh[i] - lse;
    if (t == 0) {
        s01[2 * row + 0] = L[CC0 + 0] + bh[CC0 + 0] - lse;
        s01[2 * row + 1] = L[CC0 + 1] + bh[CC0 + 1] - lse;
    }
}

// ---------------- per-row additive constants: add = s01 - log(rowsum) ----------------
__global__ __launch_bounds__(256) void prep_add_kernel(
    const float* __restrict__ s01, const float* __restrict__ rs0,
    const float* __restrict__ rs1, float* __restrict__ add0,
    float* __restrict__ add1, int n)
{
    int i = blockIdx.x * blockDim.x + threadIdx.x;
    if (i < n) {
        add0[i] = s01[2 * i + 0] - logf(rs0[i]);
        add1[i] = s01[2 * i + 1] - logf(rs1[i]);
    }
}

// ---------------- launch ----------------
extern "C" void kernel_launch(void* const* d_in, const int* in_sizes, int n_in,
                              void* d_out, int out_size, void* d_ws, size_t ws_size,
                              hipStream_t stream) {
    const float* x   = (const float*)d_in[0];
    const float* Wh  = (const float*)d_in[1];
    const float* bh  = (const float*)d_in[2];
    const float* W0a = (const float*)d_in[3];
    const float* W0b = (const float*)d_in[4];
    const float* W1a = (const float*)d_in[5];
    const float* W1b = (const float*)d_in[6];
    float* out = (float*)d_out;
    char*  ws  = (char*)d_ws;

    size_t off = 0;
    auto alloc = [&](size_t bytes) { size_t o = off; off += (bytes + 255) & ~(size_t)255; return o; };
    ushort* x_bf   = (ushort*)(ws + alloc((size_t)BATCH * DH * 2));
    ushort* Wh_bf  = (ushort*)(ws + alloc((size_t)NH_P * DH * 2));
    ushort* W0a_bf = (ushort*)(ws + alloc((size_t)DH * DH * 2));
    ushort* W0b_bf = (ushort*)(ws + alloc((size_t)N0_P * DH * 2));
    ushort* W1a_bf = (ushort*)(ws + alloc((size_t)256 * DH * 2));
    ushort* W1b_bf = (ushort*)(ws + alloc((size_t)N1_P * 256 * 2));
    ushort* h0_bf  = (ushort*)(ws + alloc((size_t)BATCH * DH * 2));
    ushort* h1_bf  = (ushort*)(ws + alloc((size_t)BATCH * 256 * 2));
    float*  headL  = (float*)(ws + alloc((size_t)BATCH * OUT_HEAD * 4));
    float*  s01    = (float*)(ws + alloc((size_t)BATCH * 2 * 4));
    float*  rs0    = (float*)(ws + alloc((size_t)BATCH * 4));
    float*  rs1    = (float*)(ws + alloc((size_t)BATCH * 4));
    float*  add0   = (float*)(ws + alloc((size_t)BATCH * 4));
    float*  add1   = (float*)(ws + alloc((size_t)BATCH * 4));
    ushort* L0     = (ushort*)(ws + alloc((size_t)BATCH * N0_P * 2));

    convert_all_kernel<<<dim3(1280, 7), 256, 0, stream>>>(
        (const float4*)x,   (ushort4*)x_bf,   BATCH * DH / 4,        BATCH * DH / 4,
        (const float4*)Wh,  (ushort4*)Wh_bf,  OUT_HEAD * DH / 4,     NH_P * DH / 4,
        (const float4*)W0a, (ushort4*)W0a_bf, DH * DH / 4,           DH * DH / 4,
        (const float4*)W0b, (ushort4*)W0b_bf, (CC1 - CC0) * DH / 4,  N0_P * DH / 4,
        (const float4*)W1a, (ushort4*)W1a_bf, 256 * DH / 4,          256 * DH / 4,
        (const float4*)W1b, (ushort4*)W1b_bf, (CC2 - CC1) * 256 / 4, N1_P * 256 / 4,
        rs0, rs1);

    // producers: h0 (256 blocks) + h1 (64) + head (512)
    gemm128x3_kernel<<<832, 256, 0, stream>>>(
        x_bf, W0a_bf, h0_bf, W1a_bf, h1_bf, Wh_bf, headL);

    // head log-softmax -> out[:, :2000] + cluster scalars
    head_lsm_kernel<<<BATCH, 256, 0, stream>>>(headL, bh, out, s01);

    // fused tails: tail0 (2048 blocks) + tail1 pass1 (10048 blocks)
    tails_gemm_kernel<<<2048 + (N1_P / 128) * 32, 256, 0, stream>>>(
        h0_bf, W0b_bf, L0, rs0, h1_bf, W1b_bf, rs1);

    // per-row additive constants
    prep_add_kernel<<<(BATCH + 255) / 256, 256, 0, stream>>>(s01, rs0, rs1, add0, add1, BATCH);

    // fused: tail1 pass2 (10048 blocks) + tail0 finalize (16384 blocks)
    p2_fin_kernel<<<(N1_P / 128) * 32 + 16384, 256, 0, stream>>>(
        h1_bf, W1b_bf, out, add1, L0, add0);
}

// Round 11
// 616.945 us; speedup vs baseline: 1.3127x; 1.3127x over previous
//
#include <hip/hip_runtime.h>
#include <hip/hip_bf16.h>
#include <math.h>

#define CC0 2000
#define CC1 10000
#define CC2 50000
#define DH  1024
#define BATCH 4096
#define OUT_HEAD (CC0 + 2)

#define N0_P 8192    // tail0 proj rows padded (8000 -> 8192),  mult of 256
#define N1_P 40192   // tail1 proj rows padded (40000 -> 40192), mult of 256
#define NH_P 2048    // head rows padded (2002 -> 2048)

typedef __attribute__((ext_vector_type(4))) float  f32x4;
typedef __attribute__((ext_vector_type(8))) __bf16 bf16x8;
typedef __attribute__((ext_vector_type(8))) short  s16x8;

__device__ __forceinline__ void gload_lds16(const void* g, void* l) {
    __builtin_amdgcn_global_load_lds(
        (const __attribute__((address_space(1))) void*)g,
        (__attribute__((address_space(3))) void*)l, 16, 0, 0);
}

// ------- fp32 -> bf16 conversions (6 segments) + rowsum zeroing (segment 6) -------
__global__ __launch_bounds__(256) void convert_all_kernel(
    const float4* __restrict__ s0, ushort4* __restrict__ d0, int n0s, int n0d,
    const float4* __restrict__ s1, ushort4* __restrict__ d1, int n1s, int n1d,
    const float4* __restrict__ s2, ushort4* __restrict__ d2, int n2s, int n2d,
    const float4* __restrict__ s3, ushort4* __restrict__ d3, int n3s, int n3d,
    const float4* __restrict__ s4, ushort4* __restrict__ d4, int n4s, int n4d,
    const float4* __restrict__ s5, ushort4* __restrict__ d5, int n5s, int n5d,
    float* __restrict__ rs0, float* __restrict__ rs1)
{
    if (blockIdx.y == 6) {
        int i = blockIdx.x * blockDim.x + threadIdx.x;
        if (i < BATCH) { rs0[i] = 0.f; rs1[i] = 0.f; }
        return;
    }
    const float4* src; ushort4* dst; int ns, nd;
    switch (blockIdx.y) {
        case 0: src = s0; dst = d0; ns = n0s; nd = n0d; break;
        case 1: src = s1; dst = d1; ns = n1s; nd = n1d; break;
        case 2: src = s2; dst = d2; ns = n2s; nd = n2d; break;
        case 3: src = s3; dst = d3; ns = n3s; nd = n3d; break;
        case 4: src = s4; dst = d4; ns = n4s; nd = n4d; break;
        default: src = s5; dst = d5; ns = n5s; nd = n5d; break;
    }
    int i = blockIdx.x * blockDim.x + threadIdx.x;
    const int stride = gridDim.x * blockDim.x;
    for (; i < nd; i += stride) {
        ushort4 o = {0, 0, 0, 0};
        if (i < ns) {
            float4 v = src[i];
            o.x = __builtin_bit_cast(unsigned short, (__bf16)v.x);
            o.y = __builtin_bit_cast(unsigned short, (__bf16)v.y);
            o.z = __builtin_bit_cast(unsigned short, (__bf16)v.z);
            o.w = __builtin_bit_cast(unsigned short, (__bf16)v.w);
        }
        dst[i] = o;
    }
}

// ------- fused small GEMMs (m97 128^2): h0 = x@W0a^T, h1 = x@W1a^T (bf16), headL = x@Wh^T (f32)
__global__ __launch_bounds__(256) void gemm128x3_kernel(
    const ushort* __restrict__ x_bf,
    const ushort* __restrict__ W0a_bf, ushort* __restrict__ h0,
    const ushort* __restrict__ W1a_bf, ushort* __restrict__ h1,
    const ushort* __restrict__ Wh_bf,  float*  __restrict__ headL)
{
    __shared__ ushort As[128 * 64];
    __shared__ ushort Bs[128 * 64];

    const int gb = blockIdx.x;
    const ushort* B; void* C;
    int N, ldC, wmode, nbx, lin;
    const int K = DH;
    if (gb < 256)      { B = W0a_bf; C = h0;    N = DH;       ldC = DH;       wmode = 1; nbx = 8;  lin = gb; }
    else if (gb < 320) { B = W1a_bf; C = h1;    N = 256;      ldC = 256;      wmode = 1; nbx = 2;  lin = gb - 256; }
    else               { B = Wh_bf;  C = headL; N = OUT_HEAD; ldC = OUT_HEAD; wmode = 2; nbx = 16; lin = gb - 320; }

    const int nwg = nbx * 32;
    const int q = nwg >> 3;
    int bid = (lin & 7) * q + (lin >> 3);
    const int bx = bid % nbx;
    const int by = bid / nbx;

    const int t = threadIdx.x;
    const int lane = t & 63;
    const int w = t >> 6;
    const int wr = w >> 1, wc = w & 1;
    const int lr = lane & 15;
    const int lg = lane >> 4;
    const int bm = by * 128;
    const int bn = bx * 128;
    const int lrow = lane >> 3;
    const int lcol = (lane & 7) * 8;

    f32x4 acc[4][4] = {};

    for (int k0 = 0; k0 < K; k0 += 64) {
        #pragma unroll
        for (int i = 0; i < 4; ++i) {
            const int seg = w * 4 + i;
            const int row = seg * 8 + lrow;
            gload_lds16(x_bf + (size_t)(bm + row) * K + k0 + lcol, &As[seg * 512]);
            gload_lds16(B + (size_t)(bn + row) * K + k0 + lcol, &Bs[seg * 512]);
        }
        __syncthreads();
        #pragma unroll
        for (int ks = 0; ks < 2; ++ks) {
            s16x8 af[4], bfr[4];
            #pragma unroll
            for (int m = 0; m < 4; ++m)
                af[m] = *(const s16x8*)&As[(wr * 64 + m * 16 + lr) * 64 + ks * 32 + lg * 8];
            #pragma unroll
            for (int n = 0; n < 4; ++n)
                bfr[n] = *(const s16x8*)&Bs[(wc * 64 + n * 16 + lr) * 64 + ks * 32 + lg * 8];
            #pragma unroll
            for (int m = 0; m < 4; ++m)
                #pragma unroll
                for (int n = 0; n < 4; ++n)
                    acc[m][n] = __builtin_amdgcn_mfma_f32_16x16x32_bf16(
                        __builtin_bit_cast(bf16x8, af[m]),
                        __builtin_bit_cast(bf16x8, bfr[n]), acc[m][n], 0, 0, 0);
        }
        __syncthreads();
    }

    #pragma unroll
    for (int m = 0; m < 4; ++m)
        #pragma unroll
        for (int r = 0; r < 4; ++r) {
            const int row = bm + wr * 64 + m * 16 + lg * 4 + r;
            #pragma unroll
            for (int n = 0; n < 4; ++n) {
                const int col = bn + wc * 64 + n * 16 + lr;
                float v = acc[m][n][r];
                if (col < N) {
                    if (wmode == 1)
                        ((ushort*)C)[(size_t)row * ldC + col] =
                            __builtin_bit_cast(unsigned short, (__bf16)v);
                    else
                        ((float*)C)[(size_t)row * ldC + col] = v;
                }
            }
        }
}

// ------- fused tail GEMMs (256^2 2-phase, issue-early/wait-late, XOR swizzle) -------
// seg0 (512 blocks):  L0 = h0 @ W0b^T (bf16) + rowsum rs0   (K=1024)
// seg1 (2512 blocks): L1 = h1 @ W1b^T (bf16) + rowsum rs1   (K=256)
__global__ __launch_bounds__(512, 1) void tails256_kernel(
    const ushort* __restrict__ h0, const ushort* __restrict__ W0b,
    ushort* __restrict__ L0, float* __restrict__ rs0,
    const ushort* __restrict__ h1, const ushort* __restrict__ W1b,
    ushort* __restrict__ L1, float* __restrict__ rs1)
{
    __shared__ ushort lds[2][2][256 * 64];   // 128 KiB

    const int gb = blockIdx.x;
    const ushort *A, *B; ushort* C; float* rsum;
    int K, N, nbx, ldC, lin;
    if (gb < 512) { A = h0; B = W0b; C = L0; rsum = rs0; K = DH;  N = CC1 - CC0; nbx = N0_P / 256; ldC = N0_P; lin = gb; }
    else          { A = h1; B = W1b; C = L1; rsum = rs1; K = 256; N = CC2 - CC1; nbx = N1_P / 256; ldC = N1_P; lin = gb - 512; }

    const int nwg = nbx * 16;
    const int q8 = nwg >> 3;
    int bid = (lin & 7) * q8 + (lin >> 3);
    const int by = bid % 16;      // panel-major: consecutive bids share B panel (bx)
    const int bx = bid / 16;
    const int bm = by * 256, bn = bx * 256;

    const int t = threadIdx.x;
    const int lane = t & 63;
    const int w = t >> 6;        // 0..7
    const int wr = w >> 2;       // 0..1  (M half)
    const int wc = w & 3;        // 0..3  (N quarter)
    const int lr = lane & 15;
    const int lg = lane >> 4;
    const int xr = (lr & 7) << 4;          // read-side XOR (bits 4-6)
    const int c0 = w * 64 + lane;          // staging chunk id (i=0)

    f32x4 acc[8][4] = {};
    const int nkt = K / 64;

    auto stage_tile = [&](int ktile, int buf) {
        const int k0 = ktile * 64;
        #pragma unroll
        for (int h = 0; h < 4; ++h) {
            const int r0 = (h >> 1) * 128;
            const int mat = h & 1;
            const ushort* gbase = mat ? B : A;
            const int brow = mat ? bn : bm;
            #pragma unroll
            for (int i = 0; i < 2; ++i) {
                const int c = i * 512 + c0;
                const int rl = c >> 3;
                const int cc = (c & 7) ^ (rl & 7);
                gload_lds16(gbase + (size_t)(brow + r0 + rl) * K + k0 + cc * 8,
                            (char*)&lds[buf][mat][0] + r0 * 128 + (i * 512 + w * 64) * 16);
            }
        }
    };

    // ---- prologue
    stage_tile(0, 0);
    asm volatile("s_waitcnt vmcnt(0)");
    __builtin_amdgcn_s_barrier();
    asm volatile("" ::: "memory");

    for (int tk = 0; tk < nkt; ++tk) {
        const int cur = tk & 1;
        if (tk + 1 < nkt) stage_tile(tk + 1, cur ^ 1);   // issue early, wait late
        const char* baseA = (const char*)&lds[cur][0][0];
        const char* baseB = (const char*)&lds[cur][1][0];

        // B fragments: read once per K-tile (8 ds_read_b128)
        s16x8 bfr[4][2];
        #pragma unroll
        for (int n_ = 0; n_ < 4; ++n_) {
            const int row = wc * 64 + n_ * 16 + lr;
            #pragma unroll
            for (int ks = 0; ks < 2; ++ks)
                bfr[n_][ks] = *(const s16x8*)(baseB + (row * 128 + ((ks * 64 + lg * 16) ^ xr)));
        }
        // A fragments: once per M-half; 32 MFMA per half
        #pragma unroll
        for (int mh = 0; mh < 2; ++mh) {
            s16x8 af[4][2];
            #pragma unroll
            for (int m_ = 0; m_ < 4; ++m_) {
                const int row = wr * 128 + (mh * 4 + m_) * 16 + lr;
                #pragma unroll
                for (int ks = 0; ks < 2; ++ks)
                    af[m_][ks] = *(const s16x8*)(baseA + (row * 128 + ((ks * 64 + lg * 16) ^ xr)));
            }
            __builtin_amdgcn_s_setprio(1);
            #pragma unroll
            for (int m_ = 0; m_ < 4; ++m_)
                #pragma unroll
                for (int n_ = 0; n_ < 4; ++n_)
                    #pragma unroll
                    for (int ks = 0; ks < 2; ++ks)
                        acc[mh * 4 + m_][n_] = __builtin_amdgcn_mfma_f32_16x16x32_bf16(
                            __builtin_bit_cast(bf16x8, af[m_][ks]),
                            __builtin_bit_cast(bf16x8, bfr[n_][ks]),
                            acc[mh * 4 + m_][n_], 0, 0, 0);
            __builtin_amdgcn_s_setprio(0);
        }
        asm volatile("s_waitcnt vmcnt(0)" ::: "memory");
        __builtin_amdgcn_s_barrier();
        asm volatile("" ::: "memory");
    }

    // ---- epilogue: bf16 store + fused sum-of-exp
    #pragma unroll
    for (int m = 0; m < 8; ++m) {
        #pragma unroll
        for (int r = 0; r < 4; ++r) {
            const int row = bm + wr * 128 + m * 16 + lg * 4 + r;
            float psum = 0.f;
            #pragma unroll
            for (int n = 0; n < 4; ++n) {
                const int col = bn + wc * 64 + n * 16 + lr;
                float v = acc[m][n][r];
                if (col < N) {
                    C[(size_t)row * ldC + col] =
                        __builtin_bit_cast(unsigned short, (__bf16)v);
                    psum += __expf(v);   // logits O(1): max-free LSE safe
                }
            }
            #pragma unroll
            for (int mm = 1; mm < 16; mm <<= 1) psum += __shfl_xor(psum, mm, 64);
            if (lr == 0) atomicAdd(&rsum[row], psum);
        }
    }
}

// ---------------- head log-softmax: one block per row ----------------
__global__ __launch_bounds__(256) void head_lsm_kernel(
    const float* __restrict__ HL, const float* __restrict__ bh,
    float* __restrict__ out, float* __restrict__ s01)
{
    const int row = blockIdx.x;
    const float* L = HL + (size_t)row * OUT_HEAD;
    const int t = threadIdx.x;
    __shared__ float red[4];

    float m = -1e30f;
    for (int i = t; i < OUT_HEAD; i += 256) m = fmaxf(m, L[i] + bh[i]);
    #pragma unroll
    for (int s = 1; s < 64; s <<= 1) m = fmaxf(m, __shfl_xor(m, s, 64));
    if ((t & 63) == 0) red[t >> 6] = m;
    __syncthreads();
    m = fmaxf(fmaxf(red[0], red[1]), fmaxf(red[2], red[3]));

    float sum = 0.f;
    for (int i = t; i < OUT_HEAD; i += 256) sum += __expf(L[i] + bh[i] - m);
    #pragma unroll
    for (int s = 1; s < 64; s <<= 1) sum += __shfl_xor(sum, s, 64);
    __syncthreads();
    if ((t & 63) == 0) red[t >> 6] = sum;
    __syncthreads();
    const float lse = m + logf(red[0] + red[1] + red[2] + red[3]);

    float* orow = out + (size_t)row * CC2;
    for (int i = t; i < CC0; i += 256) orow[i] = L[i] + bh[i] - lse;
    if (t == 0) {
        s01[2 * row + 0] = L[CC0 + 0] + bh[CC0 + 0] - lse;
        s01[2 * row + 1] = L[CC0 + 1] + bh[CC0 + 1] - lse;
    }
}

// ---------------- per-row additive constants: add = s01 - log(rowsum) ----------------
__global__ __launch_bounds__(256) void prep_add_kernel(
    const float* __restrict__ s01, const float* __restrict__ rs0,
    const float* __restrict__ rs1, float* __restrict__ add0,
    float* __restrict__ add1, int n)
{
    int i = blockIdx.x * blockDim.x + threadIdx.x;
    if (i < n) {
        add0[i] = s01[2 * i + 0] - logf(rs0[i]);
        add1[i] = s01[2 * i + 1] - logf(rs1[i]);
    }
}

// ------- fused finalize: both tails, bf16 logits -> fp32 out + add[row] -------------
// chunk c in [0,1000): tail0;  c in [1000,6000): tail1.  One ushort8 per thread.
__global__ __launch_bounds__(256) void finalize_all_kernel(
    const ushort* __restrict__ L0, const ushort* __restrict__ L1,
    const float* __restrict__ add0, const float* __restrict__ add1,
    float* __restrict__ out)
{
    const int row = blockIdx.y;
    const int c = blockIdx.x * blockDim.x + threadIdx.x;
    const ushort* src; float* dst; float add;
    if (c < 1000) {
        src = L0 + (size_t)row * N0_P + c * 8;
        dst = out + (size_t)row * CC2 + CC0 + c * 8;
        add = add0[row];
    } else if (c < 6000) {
        const int c1 = c - 1000;
        src = L1 + (size_t)row * N1_P + c1 * 8;
        dst = out + (size_t)row * CC2 + CC1 + c1 * 8;
        add = add1[row];
    } else return;
    s16x8 v = *(const s16x8*)src;
    float4 o0, o1;
    o0.x = __builtin_bit_cast(float, (unsigned)(unsigned short)v[0] << 16) + add;
    o0.y = __builtin_bit_cast(float, (unsigned)(unsigned short)v[1] << 16) + add;
    o0.z = __builtin_bit_cast(float, (unsigned)(unsigned short)v[2] << 16) + add;
    o0.w = __builtin_bit_cast(float, (unsigned)(unsigned short)v[3] << 16) + add;
    o1.x = __builtin_bit_cast(float, (unsigned)(unsigned short)v[4] << 16) + add;
    o1.y = __builtin_bit_cast(float, (unsigned)(unsigned short)v[5] << 16) + add;
    o1.z = __builtin_bit_cast(float, (unsigned)(unsigned short)v[6] << 16) + add;
    o1.w = __builtin_bit_cast(float, (unsigned)(unsigned short)v[7] << 16) + add;
    *(float4*)dst = o0;
    *(float4*)(dst + 4) = o1;
}

// ---------------- launch ----------------
extern "C" void kernel_launch(void* const* d_in, const int* in_sizes, int n_in,
                              void* d_out, int out_size, void* d_ws, size_t ws_size,
                              hipStream_t stream) {
    const float* x   = (const float*)d_in[0];
    const float* Wh  = (const float*)d_in[1];
    const float* bh  = (const float*)d_in[2];
    const float* W0a = (const float*)d_in[3];
    const float* W0b = (const float*)d_in[4];
    const float* W1a = (const float*)d_in[5];
    const float* W1b = (const float*)d_in[6];
    float* out = (float*)d_out;
    char*  ws  = (char*)d_ws;

    size_t off = 0;
    auto alloc = [&](size_t bytes) { size_t o = off; off += (bytes + 255) & ~(size_t)255; return o; };
    ushort* x_bf   = (ushort*)(ws + alloc((size_t)BATCH * DH * 2));
    ushort* Wh_bf  = (ushort*)(ws + alloc((size_t)NH_P * DH * 2));
    ushort* W0a_bf = (ushort*)(ws + alloc((size_t)DH * DH * 2));
    ushort* W0b_bf = (ushort*)(ws + alloc((size_t)N0_P * DH * 2));
    ushort* W1a_bf = (ushort*)(ws + alloc((size_t)256 * DH * 2));
    ushort* W1b_bf = (ushort*)(ws + alloc((size_t)N1_P * 256 * 2));
    ushort* h0_bf  = (ushort*)(ws + alloc((size_t)BATCH * DH * 2));
    ushort* h1_bf  = (ushort*)(ws + alloc((size_t)BATCH * 256 * 2));
    float*  headL  = (float*)(ws + alloc((size_t)BATCH * OUT_HEAD * 4));
    float*  s01    = (float*)(ws + alloc((size_t)BATCH * 2 * 4));
    float*  rs0    = (float*)(ws + alloc((size_t)BATCH * 4));
    float*  rs1    = (float*)(ws + alloc((size_t)BATCH * 4));
    float*  add0   = (float*)(ws + alloc((size_t)BATCH * 4));
    float*  add1   = (float*)(ws + alloc((size_t)BATCH * 4));
    ushort* L0     = (ushort*)(ws + alloc((size_t)BATCH * N0_P * 2));
    ushort* L1     = (ushort*)(ws + alloc((size_t)BATCH * N1_P * 2));

    convert_all_kernel<<<dim3(1280, 7), 256, 0, stream>>>(
        (const float4*)x,   (ushort4*)x_bf,   BATCH * DH / 4,        BATCH * DH / 4,
        (const float4*)Wh,  (ushort4*)Wh_bf,  OUT_HEAD * DH / 4,     NH_P * DH / 4,
        (const float4*)W0a, (ushort4*)W0a_bf, DH * DH / 4,           DH * DH / 4,
        (const float4*)W0b, (ushort4*)W0b_bf, (CC1 - CC0) * DH / 4,  N0_P * DH / 4,
        (const float4*)W1a, (ushort4*)W1a_bf, 256 * DH / 4,          256 * DH / 4,
        (const float4*)W1b, (ushort4*)W1b_bf, (CC2 - CC1) * 256 / 4, N1_P * 256 / 4,
        rs0, rs1);

    // producers: h0 (256 blocks) + h1 (64) + head (512)
    gemm128x3_kernel<<<832, 256, 0, stream>>>(
        x_bf, W0a_bf, h0_bf, W1a_bf, h1_bf, Wh_bf, headL);

    // head log-softmax -> out[:, :2000] + cluster scalars
    head_lsm_kernel<<<BATCH, 256, 0, stream>>>(headL, bh, out, s01);

    // fused tails (single GEMM pass each): bf16 logits + rowsums
    tails256_kernel<<<512 + (N1_P / 256) * 16, 512, 0, stream>>>(
        h0_bf, W0b_bf, L0, rs0, h1_bf, W1b_bf, L1, rs1);

    // per-row additive constants
    prep_add_kernel<<<(BATCH + 255) / 256, 256, 0, stream>>>(s01, rs0, rs1, add0, add1, BATCH);

    // fused finalize: both tails -> fp32 out
    finalize_all_kernel<<<dim3(24, BATCH), 256, 0, stream>>>(L0, L1, add0, add1, out);
}